// Round 8
// baseline (854.633 us; speedup 1.0000x reference)
//
#include <hip/hip_runtime.h>

#define IMG_H 4096
#define IMG_W 4096
#define RAD 4
#define TSX 128
#define TSY 16
#define NPX 8                 // pixels per thread (x)
#define LROWS (TSY + 2*RAD)   // 24
#define LCOLS (TSX + 2*RAD)   // 136; stride 136 floats = 544B, 16B-aligned

__device__ __forceinline__ int reflect_idx(int i, int n) {
    i = (i < 0) ? -i : i;
    i = (i >= n) ? (2 * n - 2 - i) : i;
    return i;
}

__global__ __launch_bounds__(256, 6) void bilateral_kernel(const float* __restrict__ in,
                                                           float* __restrict__ out) {
    __shared__ float tile[LROWS * LCOLS];   // 3264 floats = 13056 B
    const int bx = blockIdx.x * TSX;
    const int by = blockIdx.y * TSY;
    const int tid = threadIdx.x;

    const bool interior = (blockIdx.x > 0) && (blockIdx.x < (int)gridDim.x - 1) &&
                          (blockIdx.y > 0) && (blockIdx.y < (int)gridDim.y - 1);
    if (interior) {
        // 24 rows x 34 float4 = 816 coalesced 16B chunks, fully linear in LDS.
        const float* src = in + (size_t)(by - RAD) * IMG_W + (bx - RAD);
#pragma unroll
        for (int it = 0; it < 4; ++it) {
            int i = tid + it * 256;
            if (i < 816) {
                int row = i / 34;
                int col = i - row * 34;
                float4 q = *reinterpret_cast<const float4*>(src + row * IMG_W + col * 4);
                *reinterpret_cast<float4*>(&tile[row * 136 + col * 4]) = q;
            }
        }
    } else {
        for (int i = tid; i < LROWS * LCOLS; i += 256) {
            int ly = i / 136;
            int lx = i - ly * 136;
            int gy = reflect_idx(by + ly - RAD, IMG_H);
            int gx = reflect_idx(bx + lx - RAD, IMG_W);
            tile[ly * 136 + lx] = in[gy * IMG_W + gx];
        }
    }
    __syncthreads();

    // 256 threads = 16 tx (8 px wide) x 16 ty (1 px row) -> 128x16 outputs/block.
    const int tx = tid & 15;
    const int ty = tid >> 4;
    const int x0 = tx * NPX;

    constexpr float LOG2E = 1.4426950408889634f;
    constexpr float KR  = -50.0f * LOG2E;         // -log2e/(2*sigma_r^2)
    constexpr float S23 = 8388608.0f;             // 2^23
    constexpr float KRS = KR * S23;               // prescaled for Schraudolph
    constexpr float NEG2KRS = -2.0f * KRS;
    constexpr float SCS = (-LOG2E / 18.0f) * S23; // spatial log-weight, prescaled
    constexpr float BIAS = (127.0f - 0.04303f) * S23;

    // Per-pixel linear coefficient B = -2*KR'*c. (Dropped KR*c^2 term is a
    // per-pixel constant factor on w -> cancels in num/den.)
    float B[NPX], n[NPX], d[NPX];
    {
        float4 c0 = *reinterpret_cast<const float4*>(&tile[(ty + RAD) * 136 + x0 + 4]);
        float4 c1 = *reinterpret_cast<const float4*>(&tile[(ty + RAD) * 136 + x0 + 8]);
        B[0] = NEG2KRS * c0.x; B[1] = NEG2KRS * c0.y;
        B[2] = NEG2KRS * c0.z; B[3] = NEG2KRS * c0.w;
        B[4] = NEG2KRS * c1.x; B[5] = NEG2KRS * c1.y;
        B[6] = NEG2KRS * c1.z; B[7] = NEG2KRS * c1.w;
    }
#pragma unroll
    for (int p = 0; p < NPX; ++p) { n[p] = 0.f; d[p] = 0.f; }

    const float* rowp = &tile[ty * 136 + x0];

#pragma unroll 1
    for (int r = 0; r < 9; ++r) {
        float4 q0 = *reinterpret_cast<const float4*>(rowp);
        float4 q1 = *reinterpret_cast<const float4*>(rowp + 4);
        float4 q2 = *reinterpret_cast<const float4*>(rowp + 8);
        float4 q3 = *reinterpret_cast<const float4*>(rowp + 12);
        float4 q4 = *reinterpret_cast<const float4*>(rowp + 16);
        rowp += 136;
        float v[20] = {q0.x, q0.y, q0.z, q0.w, q1.x, q1.y, q1.z, q1.w,
                       q2.x, q2.y, q2.z, q2.w, q3.x, q3.y, q3.z, q3.w,
                       q4.x, q4.y, q4.z, q4.w};

        // Fold spatial dy-term into the Schraudolph bias for this row:
        // scb[dx] = (dyy + dxx)*SCS + BIAS, dy part runtime-uniform, dx part literal.
        int e = r - 4;
        float syf = (float)(e * e) * SCS;
        float scb[9];
#pragma unroll
        for (int dx = 0; dx < 9; ++dx) {
            const int dd = (dx - 4) * (dx - 4);
            scb[dx] = syf + ((float)dd * SCS + BIAS);   // one v_add_f32 each
        }

#pragma unroll
        for (int dx = 0; dx < 9; ++dx) {
#pragma unroll
            for (int p = 0; p < NPX; ++p) {
                float vv = v[dx + p];
                float t  = fmaf(KRS, vv, B[p]);
                float aa = fmaf(vv, t, scb[dx]);
                float w  = __int_as_float((int)aa);   // Schraudolph exp2
                n[p] = fmaf(w, vv, n[p]);
                d[p] += w;
            }
        }
    }

    float4 o0, o1;
    o0.x = n[0] * __builtin_amdgcn_rcpf(d[0]);
    o0.y = n[1] * __builtin_amdgcn_rcpf(d[1]);
    o0.z = n[2] * __builtin_amdgcn_rcpf(d[2]);
    o0.w = n[3] * __builtin_amdgcn_rcpf(d[3]);
    o1.x = n[4] * __builtin_amdgcn_rcpf(d[4]);
    o1.y = n[5] * __builtin_amdgcn_rcpf(d[5]);
    o1.z = n[6] * __builtin_amdgcn_rcpf(d[6]);
    o1.w = n[7] * __builtin_amdgcn_rcpf(d[7]);

    float* orow = &out[(size_t)(by + ty) * IMG_W + bx + x0];
    *reinterpret_cast<float4*>(orow)     = o0;
    *reinterpret_cast<float4*>(orow + 4) = o1;
}

extern "C" void kernel_launch(void* const* d_in, const int* in_sizes, int n_in,
                              void* d_out, int out_size, void* d_ws, size_t ws_size,
                              hipStream_t stream) {
    const float* in = (const float*)d_in[0];
    float* out = (float*)d_out;
    dim3 grid(IMG_W / TSX, IMG_H / TSY);
    bilateral_kernel<<<grid, 256, 0, stream>>>(in, out);
}

// Round 9
// 235.214 us; speedup vs baseline: 3.6334x; 3.6334x over previous
//
#include <hip/hip_runtime.h>

#define IMG_H 4096
#define IMG_W 4096
#define RAD 4
#define TSX 128
#define TSY 16
#define NPX 8                 // pixels per thread (x)
#define LROWS (TSY + 2*RAD)   // 24
#define LCOLS (TSX + 2*RAD)   // 136; stride 136 floats = 544B, 16B-aligned

__device__ __forceinline__ int reflect_idx(int i, int n) {
    i = (i < 0) ? -i : i;
    i = (i >= n) ? (2 * n - 2 - i) : i;
    return i;
}

__global__ __launch_bounds__(256, 4) void bilateral_kernel(const float* __restrict__ in,
                                                           float* __restrict__ out) {
    __shared__ float tile[LROWS * LCOLS];   // 3264 floats = 13056 B
    const int bx = blockIdx.x * TSX;
    const int by = blockIdx.y * TSY;
    const int tid = threadIdx.x;

    const bool interior = (blockIdx.x > 0) && (blockIdx.x < (int)gridDim.x - 1) &&
                          (blockIdx.y > 0) && (blockIdx.y < (int)gridDim.y - 1);
    if (interior) {
        // 24 rows x 34 float4 = 816 coalesced 16B chunks, linear into LDS.
        const float* src = in + (size_t)(by - RAD) * IMG_W + (bx - RAD);
#pragma unroll
        for (int it = 0; it < 4; ++it) {
            int i = tid + it * 256;
            if (i < 816) {
                int row = i / 34;
                int col = i - row * 34;
                float4 q = *reinterpret_cast<const float4*>(src + row * IMG_W + col * 4);
                *reinterpret_cast<float4*>(&tile[row * 136 + col * 4]) = q;
            }
        }
    } else {
        for (int i = tid; i < LROWS * LCOLS; i += 256) {
            int ly = i / 136;
            int lx = i - ly * 136;
            int gy = reflect_idx(by + ly - RAD, IMG_H);
            int gx = reflect_idx(bx + lx - RAD, IMG_W);
            tile[ly * 136 + lx] = in[gy * IMG_W + gx];
        }
    }
    __syncthreads();

    // 256 threads = 16 tx (8 px wide) x 16 ty (1 px row) -> 128x16 outputs/block.
    const int tx = tid & 15;
    const int ty = tid >> 4;
    const int x0 = tx * NPX;

    constexpr float LOG2E = 1.4426950408889634f;
    constexpr float KR  = -50.0f * LOG2E;         // -log2e/(2*sigma_r^2)
    constexpr float S23 = 8388608.0f;             // 2^23
    constexpr float KRS = KR * S23;               // prescaled for Schraudolph
    constexpr float NEG2KRS = -2.0f * KRS;
    constexpr float SCS = (-LOG2E / 18.0f) * S23; // spatial log-weight, prescaled
    constexpr float BIAS = (127.0f - 0.04303f) * S23;

    // Per-pixel linear coefficient B = -2*KR'*c. (Dropped KR*c^2 term is a
    // per-pixel constant factor on w -> cancels in num/den.)
    float B[NPX], n[NPX], d[NPX];
    {
        float4 c0 = *reinterpret_cast<const float4*>(&tile[(ty + RAD) * 136 + x0 + 4]);
        float4 c1 = *reinterpret_cast<const float4*>(&tile[(ty + RAD) * 136 + x0 + 8]);
        B[0] = NEG2KRS * c0.x; B[1] = NEG2KRS * c0.y;
        B[2] = NEG2KRS * c0.z; B[3] = NEG2KRS * c0.w;
        B[4] = NEG2KRS * c1.x; B[5] = NEG2KRS * c1.y;
        B[6] = NEG2KRS * c1.z; B[7] = NEG2KRS * c1.w;
    }
#pragma unroll
    for (int p = 0; p < NPX; ++p) { n[p] = 0.f; d[p] = 0.f; }

    const float* rowp = &tile[ty * 136 + x0];

#pragma unroll 1
    for (int r = 0; r < 9; ++r) {
        // Named float4s (no alloca -> cannot be demoted to scratch).
        const float4 q0 = *reinterpret_cast<const float4*>(rowp);
        const float4 q1 = *reinterpret_cast<const float4*>(rowp + 4);
        const float4 q2 = *reinterpret_cast<const float4*>(rowp + 8);
        const float4 q3 = *reinterpret_cast<const float4*>(rowp + 12);
        const float4 q4 = *reinterpret_cast<const float4*>(rowp + 16);
        rowp += 136;

        // Compile-time-index accessor; folds to a direct register reference.
        auto V = [&](int i) -> float {
            switch (i) {
                case 0:  return q0.x; case 1:  return q0.y; case 2:  return q0.z; case 3:  return q0.w;
                case 4:  return q1.x; case 5:  return q1.y; case 6:  return q1.z; case 7:  return q1.w;
                case 8:  return q2.x; case 9:  return q2.y; case 10: return q2.z; case 11: return q2.w;
                case 12: return q3.x; case 13: return q3.y; case 14: return q3.z; case 15: return q3.w;
                case 16: return q4.x; case 17: return q4.y; case 18: return q4.z; case 19: return q4.w;
            }
            return 0.f;
        };

        // Fold the spatial dy-term into the Schraudolph bias: one uniform mul
        // + 9 v_add_f32 (literal dx-part) per row. Named scalars, no alloca.
        int e = r - 4;
        float syf = (float)(e * e) * SCS;
        const float sc0 = syf + (16.0f * SCS + BIAS);
        const float sc1 = syf + (9.0f  * SCS + BIAS);
        const float sc2 = syf + (4.0f  * SCS + BIAS);
        const float sc3 = syf + (1.0f  * SCS + BIAS);
        const float sc4 = syf + (0.0f  * SCS + BIAS);
        const float sc5 = sc3;
        const float sc6 = sc2;
        const float sc7 = sc1;
        const float sc8 = sc0;
        auto SCB = [&](int i) -> float {
            switch (i) {
                case 0: return sc0; case 1: return sc1; case 2: return sc2;
                case 3: return sc3; case 4: return sc4; case 5: return sc5;
                case 6: return sc6; case 7: return sc7; case 8: return sc8;
            }
            return 0.f;
        };

#pragma unroll
        for (int dx = 0; dx < 9; ++dx) {
            const float sc = SCB(dx);
#pragma unroll
            for (int p = 0; p < NPX; ++p) {
                float vv = V(dx + p);
                float t  = fmaf(KRS, vv, B[p]);
                float aa = fmaf(vv, t, sc);
                float w  = __int_as_float((int)aa);   // Schraudolph exp2
                n[p] = fmaf(w, vv, n[p]);
                d[p] += w;
            }
        }
    }

    float4 o0, o1;
    o0.x = n[0] * __builtin_amdgcn_rcpf(d[0]);
    o0.y = n[1] * __builtin_amdgcn_rcpf(d[1]);
    o0.z = n[2] * __builtin_amdgcn_rcpf(d[2]);
    o0.w = n[3] * __builtin_amdgcn_rcpf(d[3]);
    o1.x = n[4] * __builtin_amdgcn_rcpf(d[4]);
    o1.y = n[5] * __builtin_amdgcn_rcpf(d[5]);
    o1.z = n[6] * __builtin_amdgcn_rcpf(d[6]);
    o1.w = n[7] * __builtin_amdgcn_rcpf(d[7]);

    float* orow = &out[(size_t)(by + ty) * IMG_W + bx + x0];
    *reinterpret_cast<float4*>(orow)     = o0;
    *reinterpret_cast<float4*>(orow + 4) = o1;
}

extern "C" void kernel_launch(void* const* d_in, const int* in_sizes, int n_in,
                              void* d_out, int out_size, void* d_ws, size_t ws_size,
                              hipStream_t stream) {
    const float* in = (const float*)d_in[0];
    float* out = (float*)d_out;
    dim3 grid(IMG_W / TSX, IMG_H / TSY);
    bilateral_kernel<<<grid, 256, 0, stream>>>(in, out);
}